// Round 1
// baseline (28917.999 us; speedup 1.0000x reference)
//
#include <hip/hip_runtime.h>
#include <hip/hip_bf16.h>

// GRU backbone: B=64 S=2048 D=256 V=256 L=4
// Phases per call: cast weights->bf16, embed, then per layer {gi GEMM, scan}, final GEMM.
// Scan: 4 blocks x 512 thr, batch-tile 16, Wh bf16 register-resident (48 frags/wave),
// gate-triple column ownership per wave, h dbuf in LDS (A-frag order), gi dbuf via global_load_lds.

#define B_ 64
#define S_ 2048
#define D_ 256
#define V_ 256
#define L_ 4

typedef short  s16x8 __attribute__((ext_vector_type(8)));
typedef float  f32x4 __attribute__((ext_vector_type(4)));

static __device__ __forceinline__ unsigned short f2b(float f){
  union { float f; unsigned int u; } v; v.f = f;
  unsigned int u = v.u;
  return (unsigned short)((u + 0x7FFFu + ((u >> 16) & 1u)) >> 16);  // RNE
}
static __device__ __forceinline__ float b2f(unsigned short s){
  union { unsigned int u; float f; } v; v.u = ((unsigned int)s) << 16; return v.f;
}

static __device__ __forceinline__ void lds_load16(void* lds, const void* g){
  __builtin_amdgcn_global_load_lds(
      (const __attribute__((address_space(1))) unsigned int*)g,
      (__attribute__((address_space(3))) unsigned int*)lds, 16, 0, 0);
}

__global__ void cast_bf16_kernel(const float* __restrict__ src,
                                 unsigned short* __restrict__ dst, int n){
  int i = blockIdx.x * 256 + threadIdx.x;
  if (i < n) dst[i] = f2b(src[i]);
}

__global__ void embed_kernel(const int* __restrict__ x, const float* __restrict__ emb,
                             unsigned short* __restrict__ seq){
  int bs = blockIdx.x;
  int d  = threadIdx.x;
  int tok = x[bs];
  seq[(size_t)bs * D_ + d] = f2b(emb[tok * D_ + d]);
}

// C[M,N] = A[M,K] * Bw[N,K]^T + bias ; A,Bw bf16 ; C bf16 or fp32 ; 128x128 tile, BK=32
template<int OUTF32>
__global__ __launch_bounds__(256) void gemm_bt(const unsigned short* __restrict__ A,
                                               const unsigned short* __restrict__ Bw,
                                               const float* __restrict__ bias,
                                               void* __restrict__ Cp,
                                               int M, int N, int K, int ldc){
  __shared__ __align__(16) unsigned short As[128 * 32];
  __shared__ __align__(16) unsigned short Bs[128 * 32];
  const int tid = threadIdx.x, lane = tid & 63, w = tid >> 6;
  const int col = lane & 15, q = lane >> 4;
  const int m0 = blockIdx.x * 128, n0 = blockIdx.y * 128;
  const int mW = (w & 1) * 64, nW = (w >> 1) * 64;
  const size_t rowb = (size_t)K * 2;

  f32x4 acc[4][4] = {};

  for (int k0 = 0; k0 < K; k0 += 32){
    __syncthreads();
    #pragma unroll
    for (int inst = 0; inst < 2; ++inst){
      int c = inst * 256 + w * 64 + lane;
      int row = c >> 2, c16 = c & 3;
      lds_load16((char*)As + (inst * 4096 + w * 1024),
                 (const char*)A  + (size_t)(m0 + row) * rowb + (size_t)k0 * 2 + c16 * 16);
      lds_load16((char*)Bs + (inst * 4096 + w * 1024),
                 (const char*)Bw + (size_t)(n0 + row) * rowb + (size_t)k0 * 2 + c16 * 16);
    }
    __syncthreads();
    s16x8 aF[4], bF[4];
    #pragma unroll
    for (int t = 0; t < 4; ++t){
      aF[t] = *(const s16x8*)&As[(mW + t * 16 + col) * 32 + q * 8];
      bF[t] = *(const s16x8*)&Bs[(nW + t * 16 + col) * 32 + q * 8];
    }
    #pragma unroll
    for (int mi = 0; mi < 4; ++mi)
      #pragma unroll
      for (int ni = 0; ni < 4; ++ni)
        acc[mi][ni] = __builtin_amdgcn_mfma_f32_16x16x32_bf16(aF[mi], bF[ni], acc[mi][ni], 0, 0, 0);
  }

  float bn[4];
  #pragma unroll
  for (int ni = 0; ni < 4; ++ni) bn[ni] = bias[n0 + nW + ni * 16 + col];
  #pragma unroll
  for (int mi = 0; mi < 4; ++mi)
    #pragma unroll
    for (int ni = 0; ni < 4; ++ni)
      #pragma unroll
      for (int i = 0; i < 4; ++i){
        int r  = m0 + mW + mi * 16 + 4 * q + i;
        int cN = n0 + nW + ni * 16 + col;
        float v = acc[mi][ni][i] + bn[ni];
        if (OUTF32) ((float*)Cp)[(size_t)r * ldc + cN] = v;
        else        ((unsigned short*)Cp)[(size_t)r * ldc + cN] = f2b(v);
      }
}

// Recurrent scan for one layer. gi: [B][S][768] bf16 ; Wh: [768][256] bf16 ; bh: [768] f32
// out: [B][S][256] bf16. Grid = 4 (batch tiles of 16), block = 512 (8 waves).
#define GSTR 1536   // gi LDS row stride (bytes) == natural row, LDS total exactly 64 KB
__global__ __launch_bounds__(512, 2) void gru_scan(const unsigned short* __restrict__ gi,
                                                   const unsigned short* __restrict__ Wh,
                                                   const float* __restrict__ bh,
                                                   unsigned short* __restrict__ outp){
  __shared__ __align__(16) unsigned short hb[2][4096];          // 16 KB: h in A-frag order
  __shared__ __align__(16) unsigned char  gib[2][16 * GSTR];    // 48 KB: gi chunk dbuf
  const int tid = threadIdx.x, lane = tid & 63, w = tid >> 6;
  const int col = lane & 15, q = lane >> 4;
  const int b0 = blockIdx.x * 16;
  const int dbase = w * 32;   // wave owns d in [dbase, dbase+32)

  // ---- load Wh fragments into registers: bw[g*2+t2][kk], B-layout (n=lane&15, k=q*8+j)
  s16x8 bw[6][8];
  float bhv[6];
  #pragma unroll
  for (int g = 0; g < 3; ++g)
    #pragma unroll
    for (int t2 = 0; t2 < 2; ++t2){
      int gcol = g * 256 + dbase + t2 * 16 + col;
      bhv[g * 2 + t2] = bh[gcol];
      #pragma unroll
      for (int kk = 0; kk < 8; ++kk)
        bw[g * 2 + t2][kk] = *(const s16x8*)(Wh + gcol * 256 + kk * 32 + q * 8);
    }

  for (int i = tid; i < 4096; i += 512) hb[0][i] = 0;   // h0 = 0

  // prologue: stage gi chunk for s=0 into gib[0] (rows 2w, 2w+1 per wave)
  {
    const int r = 2 * w;
    #pragma unroll
    for (int rr = 0; rr < 2; ++rr){
      const unsigned char* src = (const unsigned char*)gi
          + ((size_t)(b0 + r + rr) * S_ + 0) * (size_t)GSTR;
      unsigned char* dst = &gib[0][(r + rr) * GSTR];
      lds_load16(dst, src + lane * 16);
      if (lane < 32) lds_load16(dst + 1024, src + 1024 + lane * 16);
    }
  }

  float hprev[2][4] = {};
  unsigned int off4[4];
  #pragma unroll
  for (int i = 0; i < 4; ++i)
    off4[i] = (unsigned)(b0 + 4 * q + i) * (S_ * D_) + dbase + col;

  __syncthreads();

  for (int s = 0; s < S_; ++s){
    const int cur = s & 1, nxt = cur ^ 1;

    // prefetch gi for s+1
    if (s + 1 < S_){
      const int r = 2 * w;
      #pragma unroll
      for (int rr = 0; rr < 2; ++rr){
        const unsigned char* src = (const unsigned char*)gi
            + ((size_t)(b0 + r + rr) * S_ + (size_t)(s + 1)) * (size_t)GSTR;
        unsigned char* dst = &gib[nxt][(r + rr) * GSTR];
        lds_load16(dst, src + lane * 16);
        if (lane < 32) lds_load16(dst + 1024, src + 1024 + lane * 16);
      }
    }

    // gh = h @ Wh^T + bh  (acc init = bh)
    f32x4 acc[6];
    #pragma unroll
    for (int t = 0; t < 6; ++t){ f32x4 v = {bhv[t], bhv[t], bhv[t], bhv[t]}; acc[t] = v; }

    const unsigned short* hcur = hb[cur];
    s16x8 a0 = *(const s16x8*)&hcur[lane * 8];
    #pragma unroll
    for (int kk = 0; kk < 8; ++kk){
      s16x8 aN = a0;
      if (kk < 7) aN = *(const s16x8*)&hcur[(kk + 1) * 512 + lane * 8];
      #pragma unroll
      for (int t = 0; t < 6; ++t)
        acc[t] = __builtin_amdgcn_mfma_f32_16x16x32_bf16(a0, bw[t][kk], acc[t], 0, 0, 0);
      a0 = aN;
    }

    // gates + h update, all per-lane (gate-triple ownership)
    const unsigned char* gcb = gib[cur];
    #pragma unroll
    for (int t2 = 0; t2 < 2; ++t2){
      const int d = dbase + t2 * 16 + col;
      #pragma unroll
      for (int i = 0; i < 4; ++i){
        const int m = 4 * q + i;
        const unsigned char* rowp = gcb + m * GSTR;
        float giR = b2f(*(const unsigned short*)(rowp +        d * 2));
        float giZ = b2f(*(const unsigned short*)(rowp +  512 + d * 2));
        float giN = b2f(*(const unsigned short*)(rowp + 1024 + d * 2));
        float pr = acc[t2][i]     + giR;
        float pz = acc[2 + t2][i] + giZ;
        float rg = __builtin_amdgcn_rcpf(1.f + __expf(-pr));
        float zg = __builtin_amdgcn_rcpf(1.f + __expf(-pz));
        float na = giN + rg * acc[4 + t2][i];          // bh_n already inside acc (mult by r)
        float e2 = __expf(2.f * na);
        float ng = 1.f - 2.f * __builtin_amdgcn_rcpf(e2 + 1.f);   // tanh
        float hn = ng + zg * (hprev[t2][i] - ng);      // (1-z)*n + z*h
        hprev[t2][i] = hn;
        unsigned short hbits = f2b(hn);
        outp[(size_t)off4[i] + (size_t)s * D_ + t2 * 16] = hbits;
        // scatter into A-frag order for next step: k=d, lane'=m+16*((d>>3)&3), byte j=d&7
        hb[nxt][(d >> 5) * 512 + (m + 16 * ((d >> 3) & 3)) * 8 + (d & 7)] = hbits;
      }
    }
    __syncthreads();
  }
}

extern "C" void kernel_launch(void* const* d_in, const int* in_sizes, int n_in,
                              void* d_out, int out_size, void* d_ws, size_t ws_size,
                              hipStream_t stream){
  const int*   x    = (const int*)  d_in[0];
  const float* emb  = (const float*)d_in[1];
  const float* Wih  = (const float*)d_in[2];
  const float* Whh  = (const float*)d_in[3];
  const float* bih  = (const float*)d_in[4];
  const float* bhh  = (const float*)d_in[5];
  const float* Wout = (const float*)d_in[6];
  const float* bout = (const float*)d_in[7];
  float* out = (float*)d_out;

  char* ws = (char*)d_ws;
  unsigned short* seqA  = (unsigned short*)(ws);                 //  67,108,864 B
  unsigned short* seqB  = (unsigned short*)(ws +  67108864);     //  67,108,864 B
  unsigned short* gibuf = (unsigned short*)(ws + 134217728);     // 201,326,592 B [B][S][768] bf16
  unsigned short* wihB  = (unsigned short*)(ws + 335544320);     //   1,572,864 B
  unsigned short* whhB  = (unsigned short*)(ws + 337117184);     //   1,572,864 B
  unsigned short* woutB = (unsigned short*)(ws + 338690048);     //     131,072 B

  cast_bf16_kernel<<<3072, 256, 0, stream>>>(Wih,  wihB,  L_ * 768 * 256);
  cast_bf16_kernel<<<3072, 256, 0, stream>>>(Whh,  whhB,  L_ * 768 * 256);
  cast_bf16_kernel<<< 256, 256, 0, stream>>>(Wout, woutB, V_ * D_);
  embed_kernel<<<B_ * S_, 256, 0, stream>>>(x, emb, seqA);

  const int M = B_ * S_;   // 131072
  unsigned short* sIn = seqA;
  unsigned short* sOut = seqB;
  for (int l = 0; l < L_; ++l){
    gemm_bt<0><<<dim3(M / 128, 6), 256, 0, stream>>>(sIn, wihB + (size_t)l * 768 * 256,
                                                     bih + l * 768, gibuf, M, 768, 256, 768);
    gru_scan<<<4, 512, 0, stream>>>(gibuf, whhB + (size_t)l * 768 * 256, bhh + l * 768, sOut);
    unsigned short* t = sIn; sIn = sOut; sOut = t;
  }
  gemm_bt<1><<<dim3(M / 128, 2), 256, 0, stream>>>(sIn, woutB, bout, out, M, 256, 256, 256);
}